// Round 2
// baseline (95.534 us; speedup 1.0000x reference)
//
#include <hip/hip_runtime.h>

// NeighborGatherLayer3D: out[b,l,k,t,c] = (idx[l,k] >= 0) ? in[b, idx[l,k], t, c] : 0
// B=32, L=1855, K=7, T=32, C=8  -> per-(b,l,k) chunk = T*C = 256 floats = 64 float4
constexpr int B = 32;
constexpr int L = 1855;
constexpr int K = 7;
constexpr int TC4 = 64;                 // float4 per chunk (T*C/4)
constexpr long long TOTAL4 = (long long)B * L * K * TC4;  // 26,593,280

typedef float f32x4 __attribute__((ext_vector_type(4)));  // native vector: nontemporal-builtin OK

__global__ __launch_bounds__(256) void neighbor_gather_kernel(
    const f32x4* __restrict__ src4,      // inputs as float4: (B*L) x 64
    const int* __restrict__ nbr,         // (L, K)
    f32x4* __restrict__ out4)            // (B*L*K) x 64
{
    const int e = blockIdx.x * 256 + threadIdx.x;   // float4 element index, < 26.6M fits int
    const int chunk = e >> 6;            // (b*L + l)*K + k
    const int w = e & 63;                // float4 offset within chunk

    const int k  = chunk % K;            // magic-mul
    const int bl = chunk / K;            // b*L + l
    const int l  = bl % L;               // magic-mul

    // Wave-uniform load (all 64 lanes of a wave share one chunk)
    const int ni = nbr[l * K + k];

    f32x4 v = {0.f, 0.f, 0.f, 0.f};
    if (ni >= 0) {
        const int b = bl / L;
        v = src4[(size_t)(b * L + ni) * TC4 + w];
    }
    // Output is 425 MB write-once: nontemporal to keep input resident in L2/L3
    __builtin_nontemporal_store(v, &out4[e]);
}

extern "C" void kernel_launch(void* const* d_in, const int* in_sizes, int n_in,
                              void* d_out, int out_size, void* d_ws, size_t ws_size,
                              hipStream_t stream) {
    const f32x4* src4 = (const f32x4*)d_in[0];     // inputs (B,L,T,C) float32
    const int*   nbr  = (const int*)d_in[1];       // neighbor_indices (L,K) int32
    f32x4*       out4 = (f32x4*)d_out;

    const int nblocks = (int)(TOTAL4 / 256);       // 103,880 exactly (TOTAL4 % 256 == 0)
    neighbor_gather_kernel<<<nblocks, 256, 0, stream>>>(src4, nbr, out4);
}